// Round 3
// baseline (895.408 us; speedup 1.0000x reference)
//
#include <hip/hip_runtime.h>
#include <hip/hip_fp16.h>
#include <math.h>

// Problem constants (fixed by reference)
#define BATCH 4096
#define LNUM  4
#define NEIGH 32
#define FEAT  256
#define EMB   128
#define NODE_NUM 100000

#define B_TILE 4                 // batches per block
#define ROWS   (B_TILE * LNUM)   // 16 (b,l) rows per block
#define THREADS 512              // 8 waves

struct half4_t { __half2 a, b; };  // 8 bytes = 4 fp16

// ---------------------------------------------------------------------------
// Pre-pass: features fp32 -> fp16 in workspace. Streaming, ~153MB traffic.
// Runs every launch (inputs may be re-poisoned between calls).
// ---------------------------------------------------------------------------
__global__ __launch_bounds__(256) void conv_feat(const float* __restrict__ f,
                                                 __half2* __restrict__ o,
                                                 int n4) {
  int i = blockIdx.x * 256 + threadIdx.x;
  if (i < n4) {
    float4 v = ((const float4*)f)[i];
    o[i * 2 + 0] = __float22half2_rn(make_float2(v.x, v.y));
    o[i * 2 + 1] = __float22half2_rn(make_float2(v.z, v.w));
  }
}

// ---------------------------------------------------------------------------
// Fully fused kernel (structure identical to round-2; only P1's feature
// source differs by template). 8-wave blocks, 32 waves/CU.
//  P1 gather+sum:  wave w -> batch (w>>1), layers (w&1)*2+{0,1}
//  P2 h-GEMM:      wave w -> layer (w&3), output cols (w>>2)*64+lane
//  P3 scores:      wave w -> rows (w&3)*4..+3, cols (w>>2)*64+lane
//  P4a softmax+agg; P4b out GEMM + residual + L2 normalize.
// Rationale: dur tracks L2-fill bytes at ~1.95 TB/s (r0 vs r2); fp16 gather
// halves logical gather bytes AND halves the 102MB hot footprint -> better
// L2 reuse -> FETCH_SIZE should drop >2x.
// ---------------------------------------------------------------------------
template <bool FP16FEAT>
__global__ __launch_bounds__(THREADS, 8) void fused_liamne(
    const int* __restrict__ layers, const int* __restrict__ node_i,
    const int* __restrict__ neighs, const float* __restrict__ features,
    const __half2* __restrict__ feat16, const float* __restrict__ layer_embs,
    const float* __restrict__ W, const float* __restrict__ Wt,
    const float* __restrict__ Ws1, const float* __restrict__ Ws2,
    float* __restrict__ out) {
  __shared__ float sS[ROWS][FEAT];    // 16 KB; reused as sAgg in P4
  __shared__ float sH[ROWS][EMB];     // 8 KB
  __shared__ float sc2[2][ROWS];      // per-half partial scores
  __shared__ float sNrm[2][B_TILE];   // per-half partial ||.||^2

  int b0 = blockIdx.x * B_TILE;
  int tid = threadIdx.x;
  int w = tid >> 6;       // wave index 0..7
  int lane = tid & 63;

  // ---- Phase 1: gather + neighbor-sum into sS -----------------------------
  // Wave w owns batch b0+(w>>1), layers (w&1)*2 + {0,1}. 8 loads in flight
  // per jj iteration (2 layers x 4 j). Lane holds cols 4*lane..4*lane+3.
  {
    int bi = w >> 1;
    int l0 = (w & 1) * 2;
    int nIdx[2];
#pragma unroll
    for (int l = 0; l < 2; ++l) {
      const int* nbr = neighs + ((size_t)(b0 + bi) * LNUM + l0 + l) * NEIGH;
      nIdx[l] = nbr[lane & 31];  // lanes 0..31 hold the 32 indices
    }
    float4 acc[2];
#pragma unroll
    for (int l = 0; l < 2; ++l) acc[l] = make_float4(0.f, 0.f, 0.f, 0.f);

    if (FP16FEAT) {
      const half4_t* f2 = (const half4_t*)feat16;
#pragma unroll
      for (int jj = 0; jj < 8; ++jj) {     // fully unrolled: constant shfl
        half4_t v[2][4];
#pragma unroll
        for (int l = 0; l < 2; ++l)
#pragma unroll
          for (int q = 0; q < 4; ++q) {
            int n = __shfl(nIdx[l], jj * 4 + q, 64);
            v[l][q] = f2[(size_t)n * (FEAT / 4) + lane];
          }
#pragma unroll
        for (int l = 0; l < 2; ++l)
#pragma unroll
          for (int q = 0; q < 4; ++q) {
            float2 lo = __half22float2(v[l][q].a);
            float2 hi = __half22float2(v[l][q].b);
            acc[l].x += lo.x; acc[l].y += lo.y;
            acc[l].z += hi.x; acc[l].w += hi.y;
          }
      }
    } else {
      const float4* f4 = (const float4*)features;
#pragma unroll
      for (int jj = 0; jj < 8; ++jj) {
        float4 v[2][4];
#pragma unroll
        for (int l = 0; l < 2; ++l)
#pragma unroll
          for (int q = 0; q < 4; ++q) {
            int n = __shfl(nIdx[l], jj * 4 + q, 64);
            v[l][q] = f4[(size_t)n * (FEAT / 4) + lane];
          }
#pragma unroll
        for (int l = 0; l < 2; ++l)
#pragma unroll
          for (int q = 0; q < 4; ++q) {
            acc[l].x += v[l][q].x; acc[l].y += v[l][q].y;
            acc[l].z += v[l][q].z; acc[l].w += v[l][q].w;
          }
      }
    }
#pragma unroll
    for (int l = 0; l < 2; ++l)
      ((float4*)sS[bi * LNUM + l0 + l])[lane] = acc[l];
  }
  __syncthreads();

  // ---- Phase 2: sH[lb*4+l][col] = sS[lb*4+l] @ W[l], col=(w>>2)*64+lane ---
  {
    int l = w & 3, mh = w >> 2;
    const float* Wl = W + (size_t)l * FEAT * EMB + mh * 64 + lane;
    float acc[B_TILE] = {};
    for (int k = 0; k < FEAT; k += 4) {
      float4 s[B_TILE];
#pragma unroll
      for (int lb = 0; lb < B_TILE; ++lb)
        s[lb] = *(const float4*)&sS[lb * LNUM + l][k];
#pragma unroll
      for (int kk = 0; kk < 4; ++kk) {
        float wv = Wl[(size_t)(k + kk) * EMB];
#pragma unroll
        for (int lb = 0; lb < B_TILE; ++lb)
          acc[lb] += ((const float*)&s[lb])[kk] * wv;
      }
    }
#pragma unroll
    for (int lb = 0; lb < B_TILE; ++lb)
      sH[lb * LNUM + l][mh * 64 + lane] = acc[lb];
  }
  __syncthreads();

  // ---- Phase 3: partial scores: rows (w&3)*4..+3, cols (w>>2)*64+lane -----
  {
    int rg = w & 3, mh = w >> 2;
    int col = mh * 64 + lane;
    float acc[4] = {};
    for (int k = 0; k < EMB; k += 4) {
      float4 h[4];
#pragma unroll
      for (int i = 0; i < 4; ++i)
        h[i] = *(const float4*)&sH[rg * 4 + i][k];
#pragma unroll
      for (int kk = 0; kk < 4; ++kk) {
        float wv = Ws1[(size_t)(k + kk) * EMB + col];
#pragma unroll
        for (int i = 0; i < 4; ++i)
          acc[i] += ((const float*)&h[i])[kk] * wv;
      }
    }
    float w2 = Ws2[col];
#pragma unroll
    for (int i = 0; i < 4; ++i) {
      float p = tanhf(acc[i]) * w2;
#pragma unroll
      for (int m = 1; m < 64; m <<= 1) p += __shfl_xor(p, m, 64);
      if (lane == 0) sc2[mh][rg * 4 + i] = p;
    }
  }
  __syncthreads();

  // ---- Phase 4a: softmax + attention-weighted agg into sAgg (= sS) -------
  float* sAgg = &sS[0][0];  // B_TILE x EMB overlays dead sS
  {
    int lb = tid >> 7, m = tid & 127;   // 512 threads == 512 elements
    float s0 = sc2[0][lb * 4 + 0] + sc2[1][lb * 4 + 0];
    float s1 = sc2[0][lb * 4 + 1] + sc2[1][lb * 4 + 1];
    float s2 = sc2[0][lb * 4 + 2] + sc2[1][lb * 4 + 2];
    float s3 = sc2[0][lb * 4 + 3] + sc2[1][lb * 4 + 3];
    float mx = fmaxf(fmaxf(s0, s1), fmaxf(s2, s3));
    float e0 = expf(s0 - mx), e1 = expf(s1 - mx);
    float e2 = expf(s2 - mx), e3 = expf(s3 - mx);
    float inv = 1.0f / (e0 + e1 + e2 + e3);
    float a = e0 * sH[lb * 4 + 0][m] + e1 * sH[lb * 4 + 1][m] +
              e2 * sH[lb * 4 + 2][m] + e3 * sH[lb * 4 + 3][m];
    sAgg[tid] = a * inv;
  }
  __syncthreads();

  // ---- Phase 4b: wave w: batch w&3, cols (w>>2)*64+lane -------------------
  {
    int lb = w & 3, mh = w >> 2;
    int col = mh * 64 + lane;
    float ax = 0.f;
    for (int k = 0; k < EMB; ++k)
      ax += sAgg[lb * EMB + k] * Wt[(size_t)k * EMB + col];
    int b = b0 + lb;
    int node = node_i[b];
    int lay = layers[b];
    ax += layer_embs[((size_t)node * LNUM + lay) * EMB + col];
    float ss = ax * ax;
#pragma unroll
    for (int m = 1; m < 64; m <<= 1) ss += __shfl_xor(ss, m, 64);
    if (lane == 0) sNrm[mh][lb] = ss;
    __syncthreads();
    float tot = sNrm[0][lb] + sNrm[1][lb];
    float inv = 1.0f / fmaxf(sqrtf(tot), 1e-12f);
    out[(size_t)b * EMB + col] = ax * inv;
  }
}

extern "C" void kernel_launch(void* const* d_in, const int* in_sizes, int n_in,
                              void* d_out, int out_size, void* d_ws,
                              size_t ws_size, hipStream_t stream) {
  const int* layers = (const int*)d_in[0];
  const int* node_i = (const int*)d_in[1];
  const int* neighs = (const int*)d_in[2];
  const float* features = (const float*)d_in[3];
  const float* layer_embs = (const float*)d_in[4];
  const float* neigh_emb_trans = (const float*)d_in[5];
  const float* trans_weights = (const float*)d_in[6];
  const float* trans_weights_s1 = (const float*)d_in[7];
  const float* trans_weights_s2 = (const float*)d_in[8];
  float* out = (float*)d_out;

  const size_t need = (size_t)NODE_NUM * FEAT * sizeof(__half);  // 51.2 MB
  if (d_ws && ws_size >= need) {
    __half2* feat16 = (__half2*)d_ws;
    int n4 = NODE_NUM * FEAT / 4;  // 6.4M float4s
    conv_feat<<<dim3((n4 + 255) / 256), 256, 0, stream>>>(features, feat16,
                                                          n4);
    fused_liamne<true><<<dim3(BATCH / B_TILE), THREADS, 0, stream>>>(
        layers, node_i, neighs, features, feat16, layer_embs, neigh_emb_trans,
        trans_weights, trans_weights_s1, trans_weights_s2, out);
  } else {
    fused_liamne<false><<<dim3(BATCH / B_TILE), THREADS, 0, stream>>>(
        layers, node_i, neighs, features, (const __half2*)nullptr, layer_embs,
        neigh_emb_trans, trans_weights, trans_weights_s1, trans_weights_s2,
        out);
  }
}

// Round 4
// 794.154 us; speedup vs baseline: 1.1275x; 1.1275x over previous
//
#include <hip/hip_runtime.h>
#include <hip/hip_fp16.h>
#include <math.h>

// Problem constants (fixed by reference)
#define BATCH 4096
#define LNUM  4
#define NEIGH 32
#define FEAT  256
#define EMB   128
#define NODE_NUM 100000

#define B_TILE 4                 // batches per block
#define ROWS   (B_TILE * LNUM)   // 16 (b,l) rows per block
#define THREADS 512              // 8 waves

// ---------------------------------------------------------------------------
// Pre-pass: features fp32 -> fp16 in workspace (float2 = 4 halfs, 8B aligned).
// Streaming ~153MB, ~15-30us. Runs every launch (inputs re-poisoned).
// ---------------------------------------------------------------------------
__global__ __launch_bounds__(256) void conv_feat(const float* __restrict__ f,
                                                 float2* __restrict__ o,
                                                 int n4) {
  int i = blockIdx.x * 256 + threadIdx.x;
  if (i < n4) {
    float4 v = ((const float4*)f)[i];
    __half2 h0 = __float22half2_rn(make_float2(v.x, v.y));
    __half2 h1 = __float22half2_rn(make_float2(v.z, v.w));
    float2 ov;
    ov.x = __builtin_bit_cast(float, h0);
    ov.y = __builtin_bit_cast(float, h1);
    o[i] = ov;
  }
}

// ---------------------------------------------------------------------------
// Fused kernel. Structure == round-2 (144us known-good). Changes vs round-3:
//  * __launch_bounds__(512,4): 128-VGPR cap -> NO SPILLS (r3's 1GB scratch
//    traffic came from the 64-VGPR cap at (512,8)). 16 waves/CU is enough:
//    r0 (16 waves) == r2 (28 waves) == 1.95 TB/s gather fill rate.
//  * fp16 gather loads via float2 (8B-aligned) + bit-cast to __half2.
// fp16 halves gather bytes (537->268MB logical) AND footprint (102->51MB)
// against the measured ~1.95 TB/s L2-fill roof.
// ---------------------------------------------------------------------------
template <bool FP16FEAT>
__global__ __launch_bounds__(THREADS, 4) void fused_liamne(
    const int* __restrict__ layers, const int* __restrict__ node_i,
    const int* __restrict__ neighs, const float* __restrict__ features,
    const float2* __restrict__ feat16, const float* __restrict__ layer_embs,
    const float* __restrict__ W, const float* __restrict__ Wt,
    const float* __restrict__ Ws1, const float* __restrict__ Ws2,
    float* __restrict__ out) {
  __shared__ float sS[ROWS][FEAT];    // 16 KB; reused as sAgg in P4
  __shared__ float sH[ROWS][EMB];     // 8 KB
  __shared__ float sc2[2][ROWS];      // per-half partial scores
  __shared__ float sNrm[2][B_TILE];   // per-half partial ||.||^2

  int b0 = blockIdx.x * B_TILE;
  int tid = threadIdx.x;
  int w = tid >> 6;       // wave index 0..7
  int lane = tid & 63;

  // ---- Phase 1: gather + neighbor-sum into sS -----------------------------
  // Wave w owns batch b0+(w>>1), layers (w&1)*2 + {0,1}. 8 loads in flight
  // per jj iteration (2 layers x 4 j). Lane holds cols 4*lane..4*lane+3.
  {
    int bi = w >> 1;
    int l0 = (w & 1) * 2;
    int nIdx[2];
#pragma unroll
    for (int l = 0; l < 2; ++l) {
      const int* nbr = neighs + ((size_t)(b0 + bi) * LNUM + l0 + l) * NEIGH;
      nIdx[l] = nbr[lane & 31];  // lanes 0..31 hold the 32 indices
    }
    float4 acc[2];
#pragma unroll
    for (int l = 0; l < 2; ++l) acc[l] = make_float4(0.f, 0.f, 0.f, 0.f);

    if (FP16FEAT) {
#pragma unroll
      for (int jj = 0; jj < 8; ++jj) {     // fully unrolled: constant shfl
        float2 v[2][4];                     // 8B-aligned fp16x4 payloads
#pragma unroll
        for (int l = 0; l < 2; ++l)
#pragma unroll
          for (int q = 0; q < 4; ++q) {
            int n = __shfl(nIdx[l], jj * 4 + q, 64);
            v[l][q] = feat16[(size_t)n * (FEAT / 4) + lane];
          }
#pragma unroll
        for (int l = 0; l < 2; ++l)
#pragma unroll
          for (int q = 0; q < 4; ++q) {
            float2 lo =
                __half22float2(__builtin_bit_cast(__half2, v[l][q].x));
            float2 hi =
                __half22float2(__builtin_bit_cast(__half2, v[l][q].y));
            acc[l].x += lo.x; acc[l].y += lo.y;
            acc[l].z += hi.x; acc[l].w += hi.y;
          }
      }
    } else {
      const float4* f4 = (const float4*)features;
#pragma unroll
      for (int jj = 0; jj < 8; ++jj) {
        float4 v[2][4];
#pragma unroll
        for (int l = 0; l < 2; ++l)
#pragma unroll
          for (int q = 0; q < 4; ++q) {
            int n = __shfl(nIdx[l], jj * 4 + q, 64);
            v[l][q] = f4[(size_t)n * (FEAT / 4) + lane];
          }
#pragma unroll
        for (int l = 0; l < 2; ++l)
#pragma unroll
          for (int q = 0; q < 4; ++q) {
            acc[l].x += v[l][q].x; acc[l].y += v[l][q].y;
            acc[l].z += v[l][q].z; acc[l].w += v[l][q].w;
          }
      }
    }
#pragma unroll
    for (int l = 0; l < 2; ++l)
      ((float4*)sS[bi * LNUM + l0 + l])[lane] = acc[l];
  }
  __syncthreads();

  // ---- Phase 2: sH[lb*4+l][col] = sS[lb*4+l] @ W[l], col=(w>>2)*64+lane ---
  {
    int l = w & 3, mh = w >> 2;
    const float* Wl = W + (size_t)l * FEAT * EMB + mh * 64 + lane;
    float acc[B_TILE] = {};
    for (int k = 0; k < FEAT; k += 4) {
      float4 s[B_TILE];
#pragma unroll
      for (int lb = 0; lb < B_TILE; ++lb)
        s[lb] = *(const float4*)&sS[lb * LNUM + l][k];
#pragma unroll
      for (int kk = 0; kk < 4; ++kk) {
        float wv = Wl[(size_t)(k + kk) * EMB];
#pragma unroll
        for (int lb = 0; lb < B_TILE; ++lb)
          acc[lb] += ((const float*)&s[lb])[kk] * wv;
      }
    }
#pragma unroll
    for (int lb = 0; lb < B_TILE; ++lb)
      sH[lb * LNUM + l][mh * 64 + lane] = acc[lb];
  }
  __syncthreads();

  // ---- Phase 3: partial scores: rows (w&3)*4..+3, cols (w>>2)*64+lane -----
  {
    int rg = w & 3, mh = w >> 2;
    int col = mh * 64 + lane;
    float acc[4] = {};
    for (int k = 0; k < EMB; k += 4) {
      float4 h[4];
#pragma unroll
      for (int i = 0; i < 4; ++i)
        h[i] = *(const float4*)&sH[rg * 4 + i][k];
#pragma unroll
      for (int kk = 0; kk < 4; ++kk) {
        float wv = Ws1[(size_t)(k + kk) * EMB + col];
#pragma unroll
        for (int i = 0; i < 4; ++i)
          acc[i] += ((const float*)&h[i])[kk] * wv;
      }
    }
    float w2 = Ws2[col];
#pragma unroll
    for (int i = 0; i < 4; ++i) {
      float p = tanhf(acc[i]) * w2;
#pragma unroll
      for (int m = 1; m < 64; m <<= 1) p += __shfl_xor(p, m, 64);
      if (lane == 0) sc2[mh][rg * 4 + i] = p;
    }
  }
  __syncthreads();

  // ---- Phase 4a: softmax + attention-weighted agg into sAgg (= sS) -------
  float* sAgg = &sS[0][0];  // B_TILE x EMB overlays dead sS
  {
    int lb = tid >> 7, m = tid & 127;   // 512 threads == 512 elements
    float s0 = sc2[0][lb * 4 + 0] + sc2[1][lb * 4 + 0];
    float s1 = sc2[0][lb * 4 + 1] + sc2[1][lb * 4 + 1];
    float s2 = sc2[0][lb * 4 + 2] + sc2[1][lb * 4 + 2];
    float s3 = sc2[0][lb * 4 + 3] + sc2[1][lb * 4 + 3];
    float mx = fmaxf(fmaxf(s0, s1), fmaxf(s2, s3));
    float e0 = expf(s0 - mx), e1 = expf(s1 - mx);
    float e2 = expf(s2 - mx), e3 = expf(s3 - mx);
    float inv = 1.0f / (e0 + e1 + e2 + e3);
    float a = e0 * sH[lb * 4 + 0][m] + e1 * sH[lb * 4 + 1][m] +
              e2 * sH[lb * 4 + 2][m] + e3 * sH[lb * 4 + 3][m];
    sAgg[tid] = a * inv;
  }
  __syncthreads();

  // ---- Phase 4b: wave w: batch w&3, cols (w>>2)*64+lane -------------------
  {
    int lb = w & 3, mh = w >> 2;
    int col = mh * 64 + lane;
    float ax = 0.f;
    for (int k = 0; k < EMB; ++k)
      ax += sAgg[lb * EMB + k] * Wt[(size_t)k * EMB + col];
    int b = b0 + lb;
    int node = node_i[b];
    int lay = layers[b];
    ax += layer_embs[((size_t)node * LNUM + lay) * EMB + col];
    float ss = ax * ax;
#pragma unroll
    for (int m = 1; m < 64; m <<= 1) ss += __shfl_xor(ss, m, 64);
    if (lane == 0) sNrm[mh][lb] = ss;
    __syncthreads();
    float tot = sNrm[0][lb] + sNrm[1][lb];
    float inv = 1.0f / fmaxf(sqrtf(tot), 1e-12f);
    out[(size_t)b * EMB + col] = ax * inv;
  }
}

extern "C" void kernel_launch(void* const* d_in, const int* in_sizes, int n_in,
                              void* d_out, int out_size, void* d_ws,
                              size_t ws_size, hipStream_t stream) {
  const int* layers = (const int*)d_in[0];
  const int* node_i = (const int*)d_in[1];
  const int* neighs = (const int*)d_in[2];
  const float* features = (const float*)d_in[3];
  const float* layer_embs = (const float*)d_in[4];
  const float* neigh_emb_trans = (const float*)d_in[5];
  const float* trans_weights = (const float*)d_in[6];
  const float* trans_weights_s1 = (const float*)d_in[7];
  const float* trans_weights_s2 = (const float*)d_in[8];
  float* out = (float*)d_out;

  const size_t need = (size_t)NODE_NUM * FEAT * sizeof(__half);  // 51.2 MB
  if (d_ws && ws_size >= need) {
    float2* feat16 = (float2*)d_ws;
    int n4 = NODE_NUM * FEAT / 4;  // 6.4M float4s
    conv_feat<<<dim3((n4 + 255) / 256), 256, 0, stream>>>(features, feat16,
                                                          n4);
    fused_liamne<true><<<dim3(BATCH / B_TILE), THREADS, 0, stream>>>(
        layers, node_i, neighs, features, feat16, layer_embs, neigh_emb_trans,
        trans_weights, trans_weights_s1, trans_weights_s2, out);
  } else {
    fused_liamne<false><<<dim3(BATCH / B_TILE), THREADS, 0, stream>>>(
        layers, node_i, neighs, features, (const float2*)nullptr, layer_embs,
        neigh_emb_trans, trans_weights, trans_weights_s1, trans_weights_s2,
        out);
  }
}

// Round 5
// 640.144 us; speedup vs baseline: 1.3988x; 1.2406x over previous
//
#include <hip/hip_runtime.h>
#include <hip/hip_fp16.h>
#include <math.h>

// Problem constants (fixed by reference)
#define BATCH 4096
#define LNUM  4
#define NEIGH 32
#define FEAT  256
#define EMB   128
#define NODE_NUM 100000

#define B_TILE 4                 // batches per block
#define ROWS   (B_TILE * LNUM)   // 16 (b,l) rows per block
#define THREADS 512              // 8 waves

// ---------------------------------------------------------------------------
// Pre-pass: features fp32 -> fp16 in workspace (float2 = 4 halfs, 8B aligned).
// Streaming ~153MB, ~25-35us. Runs every launch (inputs re-poisoned).
// ---------------------------------------------------------------------------
__global__ __launch_bounds__(256) void conv_feat(const float* __restrict__ f,
                                                 float2* __restrict__ o,
                                                 int n4) {
  int i = blockIdx.x * 256 + threadIdx.x;
  if (i < n4) {
    float4 v = ((const float4*)f)[i];
    __half2 h0 = __float22half2_rn(make_float2(v.x, v.y));
    __half2 h1 = __float22half2_rn(make_float2(v.z, v.w));
    float2 ov;
    ov.x = __builtin_bit_cast(float, h0);
    ov.y = __builtin_bit_cast(float, h1);
    o[i] = ov;
  }
}

// ---------------------------------------------------------------------------
// Fused kernel, structure == round-2. KEY FIX vs r3/r4: __launch_bounds__'s
// 2nd arg empirically acts as min BLOCKS/CU on this toolchain:
//   (512,8) -> cap 32 VGPR (r3: reported 32, 977MB spill writes)
//   (512,4) -> cap 64 VGPR (r4: reported 64, 842MB spill writes)
//   (256,4) -> cap 128     (r0: reported 48, 2MB writes, clean)
// So use (512,2): 2 blocks/CU x 8 waves = 16 waves/CU, 128-VGPR cap, no
// spills. 16 waves/CU is enough: r0(16w) == r2(28w) at the gather roof.
// fp16 gather halves bytes (537->268MB logical) and footprint (102->51MB).
// ---------------------------------------------------------------------------
template <bool FP16FEAT>
__global__ __launch_bounds__(THREADS, 2) void fused_liamne(
    const int* __restrict__ layers, const int* __restrict__ node_i,
    const int* __restrict__ neighs, const float* __restrict__ features,
    const float2* __restrict__ feat16, const float* __restrict__ layer_embs,
    const float* __restrict__ W, const float* __restrict__ Wt,
    const float* __restrict__ Ws1, const float* __restrict__ Ws2,
    float* __restrict__ out) {
  __shared__ float sS[ROWS][FEAT];    // 16 KB; reused as sAgg in P4
  __shared__ float sH[ROWS][EMB];     // 8 KB
  __shared__ float sc2[2][ROWS];      // per-half partial scores
  __shared__ float sNrm[2][B_TILE];   // per-half partial ||.||^2

  int b0 = blockIdx.x * B_TILE;
  int tid = threadIdx.x;
  int w = tid >> 6;       // wave index 0..7
  int lane = tid & 63;

  // ---- Phase 1: gather + neighbor-sum into sS -----------------------------
  // Wave w owns batch b0+(w>>1), layers (w&1)*2 + {0,1}. 8 loads in flight
  // per jj iteration (2 layers x 4 j). Lane holds cols 4*lane..4*lane+3.
  {
    int bi = w >> 1;
    int l0 = (w & 1) * 2;
    int nIdx[2];
#pragma unroll
    for (int l = 0; l < 2; ++l) {
      const int* nbr = neighs + ((size_t)(b0 + bi) * LNUM + l0 + l) * NEIGH;
      nIdx[l] = nbr[lane & 31];  // lanes 0..31 hold the 32 indices
    }
    float4 acc[2];
#pragma unroll
    for (int l = 0; l < 2; ++l) acc[l] = make_float4(0.f, 0.f, 0.f, 0.f);

    if (FP16FEAT) {
#pragma unroll
      for (int jj = 0; jj < 8; ++jj) {     // fully unrolled: constant shfl
        float2 v[2][4];                     // 8B-aligned fp16x4 payloads
#pragma unroll
        for (int l = 0; l < 2; ++l)
#pragma unroll
          for (int q = 0; q < 4; ++q) {
            int n = __shfl(nIdx[l], jj * 4 + q, 64);
            v[l][q] = feat16[(size_t)n * (FEAT / 4) + lane];
          }
#pragma unroll
        for (int l = 0; l < 2; ++l)
#pragma unroll
          for (int q = 0; q < 4; ++q) {
            float2 lo =
                __half22float2(__builtin_bit_cast(__half2, v[l][q].x));
            float2 hi =
                __half22float2(__builtin_bit_cast(__half2, v[l][q].y));
            acc[l].x += lo.x; acc[l].y += lo.y;
            acc[l].z += hi.x; acc[l].w += hi.y;
          }
      }
    } else {
      const float4* f4 = (const float4*)features;
#pragma unroll
      for (int jj = 0; jj < 8; ++jj) {
        float4 v[2][4];
#pragma unroll
        for (int l = 0; l < 2; ++l)
#pragma unroll
          for (int q = 0; q < 4; ++q) {
            int n = __shfl(nIdx[l], jj * 4 + q, 64);
            v[l][q] = f4[(size_t)n * (FEAT / 4) + lane];
          }
#pragma unroll
        for (int l = 0; l < 2; ++l)
#pragma unroll
          for (int q = 0; q < 4; ++q) {
            acc[l].x += v[l][q].x; acc[l].y += v[l][q].y;
            acc[l].z += v[l][q].z; acc[l].w += v[l][q].w;
          }
      }
    }
#pragma unroll
    for (int l = 0; l < 2; ++l)
      ((float4*)sS[bi * LNUM + l0 + l])[lane] = acc[l];
  }
  __syncthreads();

  // ---- Phase 2: sH[lb*4+l][col] = sS[lb*4+l] @ W[l], col=(w>>2)*64+lane ---
  {
    int l = w & 3, mh = w >> 2;
    const float* Wl = W + (size_t)l * FEAT * EMB + mh * 64 + lane;
    float acc[B_TILE] = {};
    for (int k = 0; k < FEAT; k += 4) {
      float4 s[B_TILE];
#pragma unroll
      for (int lb = 0; lb < B_TILE; ++lb)
        s[lb] = *(const float4*)&sS[lb * LNUM + l][k];
#pragma unroll
      for (int kk = 0; kk < 4; ++kk) {
        float wv = Wl[(size_t)(k + kk) * EMB];
#pragma unroll
        for (int lb = 0; lb < B_TILE; ++lb)
          acc[lb] += ((const float*)&s[lb])[kk] * wv;
      }
    }
#pragma unroll
    for (int lb = 0; lb < B_TILE; ++lb)
      sH[lb * LNUM + l][mh * 64 + lane] = acc[lb];
  }
  __syncthreads();

  // ---- Phase 3: partial scores: rows (w&3)*4..+3, cols (w>>2)*64+lane -----
  {
    int rg = w & 3, mh = w >> 2;
    int col = mh * 64 + lane;
    float acc[4] = {};
    for (int k = 0; k < EMB; k += 4) {
      float4 h[4];
#pragma unroll
      for (int i = 0; i < 4; ++i)
        h[i] = *(const float4*)&sH[rg * 4 + i][k];
#pragma unroll
      for (int kk = 0; kk < 4; ++kk) {
        float wv = Ws1[(size_t)(k + kk) * EMB + col];
#pragma unroll
        for (int i = 0; i < 4; ++i)
          acc[i] += ((const float*)&h[i])[kk] * wv;
      }
    }
    float w2 = Ws2[col];
#pragma unroll
    for (int i = 0; i < 4; ++i) {
      float p = tanhf(acc[i]) * w2;
#pragma unroll
      for (int m = 1; m < 64; m <<= 1) p += __shfl_xor(p, m, 64);
      if (lane == 0) sc2[mh][rg * 4 + i] = p;
    }
  }
  __syncthreads();

  // ---- Phase 4a: softmax + attention-weighted agg into sAgg (= sS) -------
  float* sAgg = &sS[0][0];  // B_TILE x EMB overlays dead sS
  {
    int lb = tid >> 7, m = tid & 127;   // 512 threads == 512 elements
    float s0 = sc2[0][lb * 4 + 0] + sc2[1][lb * 4 + 0];
    float s1 = sc2[0][lb * 4 + 1] + sc2[1][lb * 4 + 1];
    float s2 = sc2[0][lb * 4 + 2] + sc2[1][lb * 4 + 2];
    float s3 = sc2[0][lb * 4 + 3] + sc2[1][lb * 4 + 3];
    float mx = fmaxf(fmaxf(s0, s1), fmaxf(s2, s3));
    float e0 = expf(s0 - mx), e1 = expf(s1 - mx);
    float e2 = expf(s2 - mx), e3 = expf(s3 - mx);
    float inv = 1.0f / (e0 + e1 + e2 + e3);
    float a = e0 * sH[lb * 4 + 0][m] + e1 * sH[lb * 4 + 1][m] +
              e2 * sH[lb * 4 + 2][m] + e3 * sH[lb * 4 + 3][m];
    sAgg[tid] = a * inv;
  }
  __syncthreads();

  // ---- Phase 4b: wave w: batch w&3, cols (w>>2)*64+lane -------------------
  {
    int lb = w & 3, mh = w >> 2;
    int col = mh * 64 + lane;
    float ax = 0.f;
    for (int k = 0; k < EMB; ++k)
      ax += sAgg[lb * EMB + k] * Wt[(size_t)k * EMB + col];
    int b = b0 + lb;
    int node = node_i[b];
    int lay = layers[b];
    ax += layer_embs[((size_t)node * LNUM + lay) * EMB + col];
    float ss = ax * ax;
#pragma unroll
    for (int m = 1; m < 64; m <<= 1) ss += __shfl_xor(ss, m, 64);
    if (lane == 0) sNrm[mh][lb] = ss;
    __syncthreads();
    float tot = sNrm[0][lb] + sNrm[1][lb];
    float inv = 1.0f / fmaxf(sqrtf(tot), 1e-12f);
    out[(size_t)b * EMB + col] = ax * inv;
  }
}

extern "C" void kernel_launch(void* const* d_in, const int* in_sizes, int n_in,
                              void* d_out, int out_size, void* d_ws,
                              size_t ws_size, hipStream_t stream) {
  const int* layers = (const int*)d_in[0];
  const int* node_i = (const int*)d_in[1];
  const int* neighs = (const int*)d_in[2];
  const float* features = (const float*)d_in[3];
  const float* layer_embs = (const float*)d_in[4];
  const float* neigh_emb_trans = (const float*)d_in[5];
  const float* trans_weights = (const float*)d_in[6];
  const float* trans_weights_s1 = (const float*)d_in[7];
  const float* trans_weights_s2 = (const float*)d_in[8];
  float* out = (float*)d_out;

  const size_t need = (size_t)NODE_NUM * FEAT * sizeof(__half);  // 51.2 MB
  if (d_ws && ws_size >= need) {
    float2* feat16 = (float2*)d_ws;
    int n4 = NODE_NUM * FEAT / 4;  // 6.4M float4s
    conv_feat<<<dim3((n4 + 255) / 256), 256, 0, stream>>>(features, feat16,
                                                          n4);
    fused_liamne<true><<<dim3(BATCH / B_TILE), THREADS, 0, stream>>>(
        layers, node_i, neighs, features, feat16, layer_embs, neigh_emb_trans,
        trans_weights, trans_weights_s1, trans_weights_s2, out);
  } else {
    fused_liamne<false><<<dim3(BATCH / B_TILE), THREADS, 0, stream>>>(
        layers, node_i, neighs, features, (const float2*)nullptr, layer_embs,
        neigh_emb_trans, trans_weights, trans_weights_s1, trans_weights_s2,
        out);
  }
}